// Round 1
// baseline (2309.150 us; speedup 1.0000x reference)
//
#include <hip/hip_runtime.h>

// SppPooling: out[b,gx,gy,:] = sum over nodes n in graph b with bin (gx,gy) of
//             features[n,:] / div[n]
// N=2e6, D=128, G=8, B=64. Nodes contiguous per graph; per-graph output slab
// (8*8*128 fp32 = 32 KB) accumulated in LDS, flushed once with global atomics.
//
// This revision attacks the latency bound (prev: 471 GB/s = 5.9% HBM, VALU 6%,
// all pipes idle): 4-node unroll per wave-iteration => ~2 KB of feature loads
// in flight per wave before any vmcnt wait, plus 512-thread blocks (CHUNKS=16,
// grid=1024) for full residency in one scheduling round.

#define GBINS 8
#define DIM 128
#define TILE (GBINS * GBINS * DIM)   // 8192 floats = 32 KB LDS
#define CHUNKS 16                    // blocks per graph -> 64*16 = 1024 blocks
#define NBLOCK 512                   // 8 waves
#define NWAVES (NBLOCK / 64)
#define UNROLL 4                     // nodes per wave per iteration

__global__ __launch_bounds__(NBLOCK, 4) void spp_pool_kernel(
    const float* __restrict__ features,
    const int*   __restrict__ xy,     // [N,3]: binx, biny, div
    const int*   __restrict__ bnn,    // [B] batch_num_nodes
    float*       __restrict__ out,    // [B, 8, 8, 128], pre-zeroed
    int N, int B)
{
    __shared__ float tile[TILE];

    const int g = blockIdx.x / CHUNKS;   // graph id
    const int c = blockIdx.x % CHUNKS;   // chunk within graph

    // start offset of graph g (B=64: short uniform scalar loop, L2-cached)
    int start = 0;
    for (int i = 0; i < g; ++i) start += bnn[i];
    const int cnt  = bnn[g];
    const int per  = (cnt + CHUNKS - 1) / CHUNKS;
    const int nbeg = start + c * per;
    const int nend = min(start + cnt, nbeg + per);

    for (int i = threadIdx.x; i < TILE; i += NBLOCK) tile[i] = 0.0f;
    __syncthreads();

    const int wave = threadIdx.x >> 6;
    const int lane = threadIdx.x & 63;
    const int last = nend - 1;

    // UNROLL nodes per wave per iteration: all 4 nodes' xy (12 B broadcast)
    // and feature loads (2 x 256 B coalesced per node) issue as one batch of
    // independent vmem ops before the first vmcnt wait -> ~2 KB in flight per
    // wave instead of 512 B. Tail is branchless: clamp node index to 'last'
    // and zero the weight, so addresses stay in-bounds and sums stay exact.
    for (int base = nbeg + wave * UNROLL; base < nend; base += NWAVES * UNROLL) {
        float v0[UNROLL], v1[UNROLL], inv[UNROLL];
        int   seg[UNROLL];
        #pragma unroll
        for (int u = 0; u < UNROLL; ++u) {
            const int n  = base + u;
            const int nc = (n <= last) ? n : last;      // clamped (in-bounds)
            const int x  = xy[3 * nc];
            const int y  = xy[3 * nc + 1];
            const int d  = xy[3 * nc + 2];
            inv[u] = (n <= last) ? (1.0f / (float)d) : 0.0f;
            seg[u] = (x * GBINS + y) * DIM;
            const float* __restrict__ frow = features + (size_t)nc * DIM;
            v0[u] = frow[lane];                          // 256 B coalesced
            v1[u] = frow[lane + 64];                     // 256 B coalesced
        }
        #pragma unroll
        for (int u = 0; u < UNROLL; ++u) {
            // lane-contiguous -> only 2-way bank aliasing (free on gfx950)
            atomicAdd(&tile[seg[u] + lane],      v0[u] * inv[u]);   // ds_add_f32
            atomicAdd(&tile[seg[u] + lane + 64], v1[u] * inv[u]);
        }
    }
    __syncthreads();

    // Flush 32 KB tile to global: 8192 atomics/block, 8.4M total, coalesced.
    // Target region is 2 MB -> L2/MALL-resident.
    float* __restrict__ og = out + (size_t)g * TILE;
    for (int i = threadIdx.x; i < TILE; i += NBLOCK) {
        unsafeAtomicAdd(&og[i], tile[i]);                // global_atomic_add_f32
    }
}

extern "C" void kernel_launch(void* const* d_in, const int* in_sizes, int n_in,
                              void* d_out, int out_size, void* d_ws, size_t ws_size,
                              hipStream_t stream) {
    const float* features = (const float*)d_in[0];
    const int*   xy       = (const int*)d_in[1];
    const int*   bnn      = (const int*)d_in[2];
    float*       out      = (float*)d_out;

    const int N = in_sizes[1] / 3;
    const int B = in_sizes[2];

    // d_out is re-poisoned to 0xAA before every timed launch -> must zero it.
    hipMemsetAsync(d_out, 0, (size_t)out_size * sizeof(float), stream);

    dim3 grid(B * CHUNKS), block(NBLOCK);
    spp_pool_kernel<<<grid, block, 0, stream>>>(features, xy, bnn, out, N, B);
}